// Round 4
// baseline (2209.946 us; speedup 1.0000x reference)
//
#include <hip/hip_runtime.h>
#include <hip/hip_bf16.h>
#include <stdint.h>

#define T_STEPS 1024
#define BATCH 64
#define HID 512
#define VOC 512
#define TBV (T_STEPS*BATCH*VOC)   // 33554432
#define POISON 0x7FC17FC1u       // bf16 NaN pair — h values are never NaN

typedef __attribute__((ext_vector_type(8))) short bf16x8;
typedef __attribute__((ext_vector_type(8))) unsigned short u16x8;
typedef __attribute__((ext_vector_type(4))) float f32x4;
typedef __attribute__((ext_vector_type(4))) unsigned u32x4;

__device__ __forceinline__ float bf2f(unsigned short u){
  union { unsigned i; float f; } x; x.i = ((unsigned)u)<<16; return x.f;
}
__device__ __forceinline__ unsigned short f2bf(float f){
  union { float f; unsigned i; } x; x.f = f;
  unsigned r = (x.i + 0x7fffu + ((x.i>>16)&1u))>>16;
  return (unsigned short)r;
}
__device__ __forceinline__ float sigm(float x){ return 1.0f/(1.0f+__expf(-x)); }
__device__ __forceinline__ float tanhfast(float x){
  float e = __expf(2.0f*x); return 1.0f - 2.0f/(e+1.0f);
}

// ---- pack X [B,T,V] f32 -> Xb [T*B, V] bf16 (time-major rows m = t*64+b) ----
__global__ __launch_bounds__(256) void k_pack_x(const float* __restrict__ X,
                                                unsigned short* __restrict__ Xb){
  int idx = blockIdx.x*256 + threadIdx.x;
  int m = idx >> 6, c = idx & 63;
  int b = m & 63, t = m >> 6;
  const float* src = X + ((size_t)b*T_STEPS + t)*VOC + c*8;
  u16x8 v;
  #pragma unroll
  for (int j=0;j<8;j++) v[j] = f2bf(src[j]);
  *(u16x8*)(Xb + (size_t)m*VOC + c*8) = v;
}

// ---- pack Wx4t [n=2048][k=512] bf16, n = gate*512+h ----
__global__ __launch_bounds__(256) void k_pack_wx(const float* __restrict__ wf,
                                                 const float* __restrict__ wi,
                                                 const float* __restrict__ wo,
                                                 const float* __restrict__ wc,
                                                 unsigned short* __restrict__ Wx4t){
  int idx = blockIdx.x*256 + threadIdx.x;
  int n = idx >> 6, c = idx & 63;
  const float* w = (n<512)?wf:(n<1024)?wi:(n<1536)?wo:wc;
  int h = n & 511;
  u16x8 v;
  #pragma unroll
  for (int j=0;j<8;j++) v[j] = f2bf(w[(size_t)(c*8+j)*HID + h]);
  *(u16x8*)(Wx4t + (size_t)n*HID + c*8) = v;
}

// ---- pack Wt [mat=5][col=512][k=512] bf16 ----
__global__ __launch_bounds__(256) void k_pack_wh(const float* __restrict__ whf,
                                                 const float* __restrict__ whi,
                                                 const float* __restrict__ who,
                                                 const float* __restrict__ whc,
                                                 const float* __restrict__ why,
                                                 unsigned short* __restrict__ Wt){
  int idx = blockIdx.x*256 + threadIdx.x;
  int mat = idx >> 15;
  int rem = idx & 32767;
  int col = rem >> 6, c = rem & 63;
  const float* w = (mat==0)?whf:(mat==1)?whi:(mat==2)?who:(mat==3)?whc:why;
  u16x8 v;
  #pragma unroll
  for (int j=0;j<8;j++) v[j] = f2bf(w[(size_t)(c*8+j)*HID + col]);
  *(u16x8*)(Wt + ((size_t)mat*HID + col)*HID + c*8) = v;
}

// ---- poison the h ring with bf16-NaN pairs (write-through, L2-bypass) ----
__global__ __launch_bounds__(256) void k_poison(unsigned* __restrict__ ring){
  size_t i = ((size_t)blockIdx.x*256 + threadIdx.x)*16;
  u32x4 v = {POISON, POISON, POISON, POISON};
  asm volatile("global_store_dwordx4 %0, %1, off sc0 sc1"
               :: "v"((char*)ring + i), "v"(v) : "memory");
}

// ---- init ring[0] from state, tile-major [g][row][16] (sc1 write-through) ----
__global__ __launch_bounds__(256) void k_init_h(const float* __restrict__ state,
                                                unsigned short* __restrict__ ring){
  int idx = blockIdx.x*256 + threadIdx.x;   // 4096 threads
  int row = idx >> 6, col8 = idx & 63;
  int gt = col8 >> 1, hf = col8 & 1;
  const float* src = state + (size_t)row*HID + col8*8;
  union { unsigned short us[8]; u32x4 v; } u;
  #pragma unroll
  for (int j=0;j<8;j++) u.us[j] = f2bf(src[j]);
  char* dst = (char*)ring + (((size_t)gt*64 + row)*16 + hf*8)*2;
  asm volatile("global_store_dwordx4 %0, %1, off sc0 sc1"
               :: "v"(dst), "v"(u.v) : "memory");
}

// ---- GEMM: XG[m=65536][n=2048] bf16 = Xb @ Wx4t^T ----
__global__ __launch_bounds__(256) void k_gemm_xg(const unsigned short* __restrict__ Xb,
                                                 const unsigned short* __restrict__ Wx4t,
                                                 unsigned short* __restrict__ XG){
  __shared__ unsigned short Al[128*64];
  __shared__ unsigned short Bl[128*64];
  int tid = threadIdx.x;
  int bid = blockIdx.x;
  int bn = bid & 15, bm = bid >> 4;
  int lane = tid & 63, w = tid >> 6;
  int wm = w >> 1, wn = w & 1;
  int l15 = lane & 15, l4 = lane >> 4;

  f32x4 zero = {0.f,0.f,0.f,0.f};
  f32x4 acc[4][4];
  #pragma unroll
  for (int mi=0;mi<4;mi++)
    #pragma unroll
    for (int ni=0;ni<4;ni++) acc[mi][ni] = zero;

  for (int bk=0; bk<8; ++bk){
    if (bk) __syncthreads();
    #pragma unroll
    for (int it=0; it<4; ++it){
      int L = it*4096 + tid*16;
      int r = L >> 7, ow = L & 127;
      int sw = ow ^ ((r&7)<<4);
      u16x8 va = *(const u16x8*)((const char*)Xb   + (size_t)(bm*128 + r)*1024 + bk*128 + ow);
      u16x8 vb = *(const u16x8*)((const char*)Wx4t + (size_t)(bn*128 + r)*1024 + bk*128 + ow);
      *(u16x8*)((char*)Al + r*128 + sw) = va;
      *(u16x8*)((char*)Bl + r*128 + sw) = vb;
    }
    __syncthreads();
    #pragma unroll
    for (int kt=0; kt<2; ++kt){
      int kb = kt*64 + 16*l4;
      bf16x8 af[4], bfr[4];
      #pragma unroll
      for (int mi=0;mi<4;mi++){
        int r = wm*64 + mi*16 + l15;
        af[mi] = *(const bf16x8*)((const char*)Al + r*128 + (kb ^ ((r&7)<<4)));
      }
      #pragma unroll
      for (int ni=0;ni<4;ni++){
        int r = wn*64 + ni*16 + l15;
        bfr[ni] = *(const bf16x8*)((const char*)Bl + r*128 + (kb ^ ((r&7)<<4)));
      }
      #pragma unroll
      for (int mi=0;mi<4;mi++)
        #pragma unroll
        for (int ni=0;ni<4;ni++)
          acc[mi][ni] = __builtin_amdgcn_mfma_f32_16x16x32_bf16(af[mi], bfr[ni], acc[mi][ni], 0,0,0);
    }
  }
  #pragma unroll
  for (int mi=0;mi<4;mi++){
    int rowb = bm*128 + wm*64 + mi*16 + l4*4;
    #pragma unroll
    for (int ni=0;ni<4;ni++){
      int col = bn*128 + wn*64 + ni*16 + l15;
      #pragma unroll
      for (int r=0;r<4;r++)
        XG[(size_t)(rowb+r)*2048 + col] = f2bf(acc[mi][ni][r]);
    }
  }
}

// ---- persistent LSTM scan: 4 groups x 32 blocks, 320 threads (5 waves) ----
// h ring: 1025 slots, tile-major [g=32][row=64][16 cols] bf16 (65536 B/slot).
// Data-is-the-flag: slots pre-poisoned with bf16 NaN; consumers poll their
// 16KB row-slice with sc0 sc1 dwordx4 loads until no dword == POISON.
// Producers: coalesced fire-and-forget 2B sc1 stores (no drain, no flag).
// Own tile never round-trips: kept in LDS via ds_write at cell update.
__global__ __launch_bounds__(320) void k_scan(
  const unsigned short* __restrict__ XG, const unsigned short* __restrict__ Wt,
  unsigned short* __restrict__ ring,
  const float* __restrict__ cand,
  const float* __restrict__ b_f, const float* __restrict__ b_i,
  const float* __restrict__ b_o, const float* __restrict__ b_c,
  const float* __restrict__ b_y,
  float* __restrict__ out)
{
  __shared__ char h_lds[16*1024];        // swizzled h(t) slice [16 rows][1024B]
  __shared__ float gate_lds[4][16][20];
  int tid = threadIdx.x;
  int w = tid >> 6, lane = tid & 63;
  int l15 = lane & 15, l4 = lane >> 4;
  int grp = blockIdx.x >> 5, g = blockIdx.x & 31;
  int colbase = g*16, rowbase = grp*16;

  // --- W_h fragments resident in registers (asm loads can't be rematerialized) ---
  u32x4 breg[16];
  {
    const char* wb = (const char*)Wt + ((size_t)(w*HID + colbase + l15))*HID*2 + l4*16;
    #pragma unroll
    for (int kt=0; kt<16; ++kt)
      asm volatile("global_load_dwordx4 %0, %1, off" : "=v"(breg[kt]) : "v"(wb + kt*64));
    asm volatile("s_waitcnt vmcnt(0)" ::: "memory");
    __builtin_amdgcn_sched_barrier(0);
  }

  // --- per-thread cell state + biases in registers (tid<256: one cell each) ---
  int cr = tid >> 4, cc = tid & 15;
  int colg = colbase + cc, browg = rowbase + cr;
  float c_val = 0.f, bfv=0.f, biv=0.f, bov=0.f, bcv=0.f;
  if (tid < 256){
    c_val = cand[(size_t)browg*HID + colg];
    bfv = b_f[colg]; biv = b_i[colg]; bov = b_o[colg]; bcv = b_c[colg];
  }
  float byv = (w==4) ? b_y[colbase + l15] : 0.f;

  // --- staging chunk geometry (4 x 16B per thread, tid<256) ---
  int rr = (tid>>1) & 15, hf = tid & 1;
  int g0 = tid >> 5;
  int off32[4], ldsw[4]; bool ownj[4];
  #pragma unroll
  for (int j=0;j<4;j++){
    int gj = g0 + 8*j;
    off32[j] = gj*2048 + (rowbase+rr)*32 + hf*16;
    ldsw[j]  = rr*1024 + ((gj*32 + hf*16) ^ ((rr&7)<<4));
    ownj[j]  = (gj == g);
  }

  for (int t=0; t<=T_STEPS; ++t){
    // --- XG(t) prefetch (L2; latency hides under the poll) ---
    float xf_r=0.f, xi_r=0.f, xo_r=0.f, xc_r=0.f;
    if (t < T_STEPS && tid < 256){
      const unsigned short* xg = XG + ((size_t)t*64 + browg)*2048 + colg;
      xf_r = bf2f(xg[0]);    xi_r = bf2f(xg[512]);
      xo_r = bf2f(xg[1024]); xc_r = bf2f(xg[1536]);
    }
    // --- poll + stage h(t) slice (skip own tile when t>0) ---
    const char* rt = (const char*)ring + (size_t)t*65536;
    if (tid < 256){
      const char* p0 = rt + off32[0];
      const char* p1 = rt + off32[1];
      const char* p2 = rt + off32[2];
      const char* p3 = rt + off32[3];
      u32x4 h0, h1, h2, h3;
      for (;;){
        asm volatile(
          "global_load_dwordx4 %0, %4, off sc0 sc1\n\t"
          "global_load_dwordx4 %1, %5, off sc0 sc1\n\t"
          "global_load_dwordx4 %2, %6, off sc0 sc1\n\t"
          "global_load_dwordx4 %3, %7, off sc0 sc1\n\t"
          "s_waitcnt vmcnt(0)"
          : "=&v"(h0), "=&v"(h1), "=&v"(h2), "=&v"(h3)
          : "v"(p0), "v"(p1), "v"(p2), "v"(p3)
          : "memory");
        bool ok = true;
        if (!(ownj[0] && t>0)) ok &= (h0[0]!=POISON)&(h0[1]!=POISON)&(h0[2]!=POISON)&(h0[3]!=POISON);
        if (!(ownj[1] && t>0)) ok &= (h1[0]!=POISON)&(h1[1]!=POISON)&(h1[2]!=POISON)&(h1[3]!=POISON);
        if (!(ownj[2] && t>0)) ok &= (h2[0]!=POISON)&(h2[1]!=POISON)&(h2[2]!=POISON)&(h2[3]!=POISON);
        if (!(ownj[3] && t>0)) ok &= (h3[0]!=POISON)&(h3[1]!=POISON)&(h3[2]!=POISON)&(h3[3]!=POISON);
        if (ok) break;
        __builtin_amdgcn_s_sleep(1);
      }
      if (!(ownj[0] && t>0)) *(u32x4*)(h_lds + ldsw[0]) = h0;
      if (!(ownj[1] && t>0)) *(u32x4*)(h_lds + ldsw[1]) = h1;
      if (!(ownj[2] && t>0)) *(u32x4*)(h_lds + ldsw[2]) = h2;
      if (!(ownj[3] && t>0)) *(u32x4*)(h_lds + ldsw[3]) = h3;
    }
    __syncthreads();

    // --- 16x16 MFMA: accv = h(t) @ W[w] for this block's 16 cols ---
    f32x4 acc0 = {0.f,0.f,0.f,0.f}, acc1 = {0.f,0.f,0.f,0.f};
    #pragma unroll
    for (int kt=0; kt<16; kt+=2){
      bf16x8 a0 = *(const bf16x8*)(h_lds + l15*1024 + (((kt  )*64 + l4*16) ^ ((l15&7)<<4)));
      bf16x8 a1 = *(const bf16x8*)(h_lds + l15*1024 + (((kt+1)*64 + l4*16) ^ ((l15&7)<<4)));
      acc0 = __builtin_amdgcn_mfma_f32_16x16x32_bf16(a0, __builtin_bit_cast(bf16x8, breg[kt]),   acc0, 0,0,0);
      acc1 = __builtin_amdgcn_mfma_f32_16x16x32_bf16(a1, __builtin_bit_cast(bf16x8, breg[kt+1]), acc1, 0,0,0);
    }
    f32x4 accv = acc0 + acc1;

    if (w < 4){
      if (t < T_STEPS){
        #pragma unroll
        for (int r=0;r<4;r++) gate_lds[w][l4*4+r][l15] = accv[r];
      }
    } else if (t >= 1){
      #pragma unroll
      for (int r=0;r<4;r++)
        out[((size_t)(t-1)*64 + rowbase + l4*4 + r)*VOC + colbase + l15] = accv[r] + byv;
    }
    __syncthreads();

    // --- cell update; h(t+1) -> own LDS tile + coalesced fire-and-forget ring store ---
    if (t < T_STEPS && tid < 256){
      float gf = xf_r + bfv + gate_lds[0][cr][cc];
      float gi = xi_r + biv + gate_lds[1][cr][cc];
      float go = xo_r + bov + gate_lds[2][cr][cc];
      float gc = xc_r + bcv + gate_lds[3][cr][cc];
      float fv = sigm(gf), iv = sigm(gi), ov = sigm(go);
      c_val = fv*c_val + iv*tanhfast(gc);
      float hvf = ov*tanhfast(c_val);
      unsigned hb16 = f2bf(hvf);
      // own tile into LDS for step t+1 (staging skips it)
      *(unsigned short*)(h_lds + cr*1024 + ((g*32 + cc*2) ^ ((cr&7)<<4))) = (unsigned short)hb16;
      // ring store: 256 consecutive 2B -> full 64B lines, no drain needed
      char* hp = (char*)ring + (size_t)(t+1)*65536 + g*2048 + (rowbase+cr)*32 + cc*2;
      asm volatile("global_store_short %0, %1, off sc0 sc1"
                   :: "v"(hp), "v"(hb16) : "memory");
      if (t == T_STEPS-1){
        out[(size_t)TBV + (size_t)browg*512 + colg] = hvf;
        out[(size_t)TBV + 32768 + (size_t)browg*512 + colg] = c_val;
      }
    }
  }
}

extern "C" void kernel_launch(void* const* d_in, const int* in_sizes, int n_in,
                              void* d_out, int out_size, void* d_ws, size_t ws_size,
                              hipStream_t stream){
  const float* X    = (const float*)d_in[0];
  const float* state= (const float*)d_in[1];
  const float* cand = (const float*)d_in[2];
  const float* w_xf = (const float*)d_in[3];
  const float* w_hf = (const float*)d_in[4];
  const float* b_f  = (const float*)d_in[5];
  const float* w_xi = (const float*)d_in[6];
  const float* w_hi = (const float*)d_in[7];
  const float* b_i  = (const float*)d_in[8];
  const float* w_xo = (const float*)d_in[9];
  const float* w_ho = (const float*)d_in[10];
  const float* b_o  = (const float*)d_in[11];
  const float* w_xc = (const float*)d_in[12];
  const float* w_hc = (const float*)d_in[13];
  const float* b_c  = (const float*)d_in[14];
  const float* w_hy = (const float*)d_in[15];
  const float* b_y  = (const float*)d_in[16];
  float* out = (float*)d_out;

  char* ws = (char*)d_ws;
  unsigned short* XG   = (unsigned short*)(ws);                 // 268,435,456 B
  // ring ALIASES Xb: Xb is consumed by k_gemm_xg, then poisoned as the h ring.
  unsigned short* Xb   = (unsigned short*)(ws + 268435456);     //  67,108,864 B
  unsigned short* ring = (unsigned short*)(ws + 268435456);     //  67,174,400 B (1025*65536)
  unsigned short* Wx4t = (unsigned short*)(ws + 335609856);     //   2,097,152 B
  unsigned short* Wt   = (unsigned short*)(ws + 337707008);     //   2,621,440 B -> end 340,328,448

  k_pack_x <<<16384,256,0,stream>>>(X, Xb);
  k_pack_wx<<<  512,256,0,stream>>>(w_xf,w_xi,w_xo,w_xc, Wx4t);
  k_pack_wh<<<  640,256,0,stream>>>(w_hf,w_hi,w_ho,w_hc,w_hy, Wt);
  k_gemm_xg<<< 8192,256,0,stream>>>(Xb, Wx4t, XG);
  k_poison <<<16400,256,0,stream>>>((unsigned*)ring);
  k_init_h <<<   16,256,0,stream>>>(state, ring);
  k_scan   <<<  128,320,0,stream>>>(XG, Wt, ring, cand, b_f,b_i,b_o,b_c,b_y, out);
}

// Round 9
// 2156.686 us; speedup vs baseline: 1.0247x; 1.0247x over previous
//
#include <hip/hip_runtime.h>
#include <hip/hip_bf16.h>
#include <stdint.h>

#define T_STEPS 1024
#define BATCH 64
#define HID 512
#define VOC 512
#define TBV (T_STEPS*BATCH*VOC)   // 33554432
#define POISON 0x7FC17FC1u       // bf16 NaN pair — h values are never NaN

typedef __attribute__((ext_vector_type(8))) short bf16x8;
typedef __attribute__((ext_vector_type(8))) unsigned short u16x8;
typedef __attribute__((ext_vector_type(4))) float f32x4;
typedef __attribute__((ext_vector_type(4))) unsigned u32x4;
typedef __attribute__((ext_vector_type(2))) unsigned u32x2;

__device__ __forceinline__ float bf2f(unsigned short u){
  union { unsigned i; float f; } x; x.i = ((unsigned)u)<<16; return x.f;
}
__device__ __forceinline__ unsigned short f2bf(float f){
  union { float f; unsigned i; } x; x.f = f;
  unsigned r = (x.i + 0x7fffu + ((x.i>>16)&1u))>>16;
  return (unsigned short)r;
}
__device__ __forceinline__ float sigm(float x){ return 1.0f/(1.0f+__expf(-x)); }
__device__ __forceinline__ float tanhfast(float x){
  float e = __expf(2.0f*x); return 1.0f - 2.0f/(e+1.0f);
}

// ---- pack X [B,T,V] f32 -> Xb [T*B, V] bf16 (time-major rows m = t*64+b) ----
__global__ __launch_bounds__(256) void k_pack_x(const float* __restrict__ X,
                                                unsigned short* __restrict__ Xb){
  int idx = blockIdx.x*256 + threadIdx.x;
  int m = idx >> 6, c = idx & 63;
  int b = m & 63, t = m >> 6;
  const float* src = X + ((size_t)b*T_STEPS + t)*VOC + c*8;
  u16x8 v;
  #pragma unroll
  for (int j=0;j<8;j++) v[j] = f2bf(src[j]);
  *(u16x8*)(Xb + (size_t)m*VOC + c*8) = v;
}

// ---- pack Wx4t [n=2048][k=512] bf16, n = gate*512+h ----
__global__ __launch_bounds__(256) void k_pack_wx(const float* __restrict__ wf,
                                                 const float* __restrict__ wi,
                                                 const float* __restrict__ wo,
                                                 const float* __restrict__ wc,
                                                 unsigned short* __restrict__ Wx4t){
  int idx = blockIdx.x*256 + threadIdx.x;
  int n = idx >> 6, c = idx & 63;
  const float* w = (n<512)?wf:(n<1024)?wi:(n<1536)?wo:wc;
  int h = n & 511;
  u16x8 v;
  #pragma unroll
  for (int j=0;j<8;j++) v[j] = f2bf(w[(size_t)(c*8+j)*HID + h]);
  *(u16x8*)(Wx4t + (size_t)n*HID + c*8) = v;
}

// ---- pack Wt [mat=5][col=512][k=512] bf16 ----
__global__ __launch_bounds__(256) void k_pack_wh(const float* __restrict__ whf,
                                                 const float* __restrict__ whi,
                                                 const float* __restrict__ who,
                                                 const float* __restrict__ whc,
                                                 const float* __restrict__ why,
                                                 unsigned short* __restrict__ Wt){
  int idx = blockIdx.x*256 + threadIdx.x;
  int mat = idx >> 15;
  int rem = idx & 32767;
  int col = rem >> 6, c = rem & 63;
  const float* w = (mat==0)?whf:(mat==1)?whi:(mat==2)?who:(mat==3)?whc:why;
  u16x8 v;
  #pragma unroll
  for (int j=0;j<8;j++) v[j] = f2bf(w[(size_t)(c*8+j)*HID + col]);
  *(u16x8*)(Wt + ((size_t)mat*HID + col)*HID + c*8) = v;
}

// ---- poison the h ring with bf16-NaN pairs (write-through, L2-bypass) ----
__global__ __launch_bounds__(256) void k_poison(unsigned* __restrict__ ring){
  size_t i = ((size_t)blockIdx.x*256 + threadIdx.x)*16;
  u32x4 v = {POISON, POISON, POISON, POISON};
  asm volatile("global_store_dwordx4 %0, %1, off sc0 sc1"
               :: "v"((char*)ring + i), "v"(v) : "memory");
}

// ---- init ring[0] from state, tile-major [g 32][row 64][col 16] ----
__global__ __launch_bounds__(256) void k_init_h(const float* __restrict__ state,
                                                unsigned short* __restrict__ ring){
  int idx = blockIdx.x*256 + threadIdx.x;   // 4096 threads
  int row = idx >> 6, col8 = idx & 63;
  int gt = col8 >> 1, hf = col8 & 1;
  const float* src = state + (size_t)row*HID + col8*8;
  union { unsigned short us[8]; u32x4 v; } u;
  #pragma unroll
  for (int j=0;j<8;j++) u.us[j] = f2bf(src[j]);
  char* dst = (char*)ring + (((size_t)gt*64 + row)*16 + hf*8)*2;
  asm volatile("global_store_dwordx4 %0, %1, off sc0 sc1"
               :: "v"(dst), "v"(u.v) : "memory");
}

// ---- GEMM: XG2 = Xb @ Wx4t^T; epilogue packs [t][grp][g][gate][cell 256] ----
// Chunk (t,grp,g) = 2KB: gate-major, cell = r16*16+c row-major — the scan
// block's 256 cell-threads read cell==tid contiguously (128B/gate/wave).
__global__ __launch_bounds__(256) void k_gemm_xg(const unsigned short* __restrict__ Xb,
                                                 const unsigned short* __restrict__ Wx4t,
                                                 unsigned short* __restrict__ XG2){
  __shared__ unsigned short Al[128*64];
  __shared__ unsigned short Bl[128*64];
  int tid = threadIdx.x;
  int bid = blockIdx.x;
  int bn = bid & 15, bm = bid >> 4;
  int lane = tid & 63, w = tid >> 6;
  int wm = w >> 1, wn = w & 1;
  int l15 = lane & 15, l4 = lane >> 4;

  f32x4 zero = {0.f,0.f,0.f,0.f};
  f32x4 acc[4][4];
  #pragma unroll
  for (int mi=0;mi<4;mi++)
    #pragma unroll
    for (int ni=0;ni<4;ni++) acc[mi][ni] = zero;

  for (int bk=0; bk<8; ++bk){
    if (bk) __syncthreads();
    #pragma unroll
    for (int it=0; it<4; ++it){
      int L = it*4096 + tid*16;
      int r = L >> 7, ow = L & 127;
      int sw = ow ^ ((r&7)<<4);
      u16x8 va = *(const u16x8*)((const char*)Xb   + (size_t)(bm*128 + r)*1024 + bk*128 + ow);
      u16x8 vb = *(const u16x8*)((const char*)Wx4t + (size_t)(bn*128 + r)*1024 + bk*128 + ow);
      *(u16x8*)((char*)Al + r*128 + sw) = va;
      *(u16x8*)((char*)Bl + r*128 + sw) = vb;
    }
    __syncthreads();
    #pragma unroll
    for (int kt=0; kt<2; ++kt){
      int kb = kt*64 + 16*l4;
      bf16x8 af[4], bfr[4];
      #pragma unroll
      for (int mi=0;mi<4;mi++){
        int r = wm*64 + mi*16 + l15;
        af[mi] = *(const bf16x8*)((const char*)Al + r*128 + (kb ^ ((r&7)<<4)));
      }
      #pragma unroll
      for (int ni=0;ni<4;ni++){
        int r = wn*64 + ni*16 + l15;
        bfr[ni] = *(const bf16x8*)((const char*)Bl + r*128 + (kb ^ ((r&7)<<4)));
      }
      #pragma unroll
      for (int mi=0;mi<4;mi++)
        #pragma unroll
        for (int ni=0;ni<4;ni++)
          acc[mi][ni] = __builtin_amdgcn_mfma_f32_16x16x32_bf16(af[mi], bfr[ni], acc[mi][ni], 0,0,0);
    }
  }
  // m = bm*128+wm*64+mi*16+l4*4+rr -> t = bm*2+wm, grp = mi, r16 = l4*4+rr
  // col = bn*128+wn*64+ni*16+l15 -> gate = col>>9, g = (col>>4)&31, c = l15
  int t0 = bm*2 + wm;
  #pragma unroll
  for (int mi=0;mi<4;mi++){
    #pragma unroll
    for (int ni=0;ni<4;ni++){
      int col = bn*128 + wn*64 + ni*16;
      int gate = col >> 9, gg = (col >> 4) & 31;
      size_t base = (((size_t)t0*4 + mi)*32 + gg)*1024 + (size_t)gate*256 + l15;
      #pragma unroll
      for (int rr=0;rr<4;rr++)
        XG2[base + (size_t)(l4*4+rr)*16] = f2bf(acc[mi][ni][rr]);
    }
  }
}

// ---- persistent LSTM scan: 4 groups x 32 blocks, 320 threads (5 waves) ----
// h ring: 1025 slots, tile-major [g=32][row=64][16 cols] bf16 (65536 B/slot).
// Data-is-the-flag: slots pre-poisoned with bf16 NaN; consumers poll their
// 16KB row-slice with sc0 sc1 dwordx4 loads until no dword == POISON.
// Producers: coalesced fire-and-forget 2B sc1 stores (no drain, no flag).
// Own tile never round-trips: kept in LDS via ds_write at cell update.
// XG2 is read one step AHEAD (pipelined) so its latency never sits inside
// the poll's vmcnt(0) drain.
__global__ __launch_bounds__(320) void k_scan(
  const unsigned short* __restrict__ XG2, const unsigned short* __restrict__ Wt,
  unsigned short* __restrict__ ring,
  const float* __restrict__ cand,
  const float* __restrict__ b_f, const float* __restrict__ b_i,
  const float* __restrict__ b_o, const float* __restrict__ b_c,
  const float* __restrict__ b_y,
  float* __restrict__ out)
{
  __shared__ char h_lds[16*1024];        // swizzled h(t) slice [16 rows][1024B]
  __shared__ float gate_lds[4][16][20];
  int tid = threadIdx.x;
  int w = tid >> 6, lane = tid & 63;
  int l15 = lane & 15, l4 = lane >> 4;
  int grp = blockIdx.x >> 5, g = blockIdx.x & 31;
  int colbase = g*16, rowbase = grp*16;

  // --- W_h fragments resident in registers (asm loads can't be rematerialized) ---
  u32x4 breg[16];
  {
    const char* wb = (const char*)Wt + ((size_t)(w*HID + colbase + l15))*HID*2 + l4*16;
    #pragma unroll
    for (int kt=0; kt<16; ++kt)
      asm volatile("global_load_dwordx4 %0, %1, off" : "=v"(breg[kt]) : "v"(wb + kt*64));
    asm volatile("s_waitcnt vmcnt(0)" ::: "memory");
    __builtin_amdgcn_sched_barrier(0);
  }

  // --- per-thread cell state + biases in registers (tid<256: one cell each) ---
  int cr = tid >> 4, cc = tid & 15;
  int colg = colbase + cc, browg = rowbase + cr;
  float c_val = 0.f, bfv=0.f, biv=0.f, bov=0.f, bcv=0.f;
  if (tid < 256){
    c_val = cand[(size_t)browg*HID + colg];
    bfv = b_f[colg]; biv = b_i[colg]; bov = b_o[colg]; bcv = b_c[colg];
  }
  float byv = (w==4) ? b_y[colbase + l15] : 0.f;

  // --- staging chunk geometry (4 x 16B per thread, tid<256) ---
  int rr = (tid>>1) & 15, hf = tid & 1;
  int g0 = tid >> 5;
  int off32[4], ldsw[4]; bool ownj[4];
  #pragma unroll
  for (int j=0;j<4;j++){
    int gj = g0 + 8*j;
    off32[j] = gj*2048 + (rowbase+rr)*32 + hf*16;
    ldsw[j]  = rr*1024 + ((gj*32 + hf*16) ^ ((rr&7)<<4));
    ownj[j]  = (gj == g);
  }

  // --- XG pipeline: xg(0) loaded before the loop, xg(t+1) during step t ---
  unsigned short xgf=0, xgi=0, xgo=0, xgc=0;
  if (tid < 256){
    const unsigned short* x0 = XG2 + ((size_t)grp*32 + g)*1024;
    xgf = x0[tid]; xgi = x0[256+tid]; xgo = x0[512+tid]; xgc = x0[768+tid];
  }

  for (int t=0; t<=T_STEPS; ++t){
    // --- poll + stage h(t) slice (skip own tile when t>0) ---
    const char* rt = (const char*)ring + (size_t)t*65536;
    if (tid < 256){
      const char* p0 = rt + off32[0];
      const char* p1 = rt + off32[1];
      const char* p2 = rt + off32[2];
      const char* p3 = rt + off32[3];
      u32x4 h0, h1, h2, h3;
      for (;;){
        asm volatile(
          "global_load_dwordx4 %0, %4, off sc0 sc1\n\t"
          "global_load_dwordx4 %1, %5, off sc0 sc1\n\t"
          "global_load_dwordx4 %2, %6, off sc0 sc1\n\t"
          "global_load_dwordx4 %3, %7, off sc0 sc1\n\t"
          "s_waitcnt vmcnt(0)"
          : "=&v"(h0), "=&v"(h1), "=&v"(h2), "=&v"(h3)
          : "v"(p0), "v"(p1), "v"(p2), "v"(p3)
          : "memory");
        bool ok = true;
        if (!(ownj[0] && t>0)) ok &= (h0[0]!=POISON)&(h0[1]!=POISON)&(h0[2]!=POISON)&(h0[3]!=POISON);
        if (!(ownj[1] && t>0)) ok &= (h1[0]!=POISON)&(h1[1]!=POISON)&(h1[2]!=POISON)&(h1[3]!=POISON);
        if (!(ownj[2] && t>0)) ok &= (h2[0]!=POISON)&(h2[1]!=POISON)&(h2[2]!=POISON)&(h2[3]!=POISON);
        if (!(ownj[3] && t>0)) ok &= (h3[0]!=POISON)&(h3[1]!=POISON)&(h3[2]!=POISON)&(h3[3]!=POISON);
        if (ok) break;
        __builtin_amdgcn_s_sleep(1);
      }
      if (!(ownj[0] && t>0)) *(u32x4*)(h_lds + ldsw[0]) = h0;
      if (!(ownj[1] && t>0)) *(u32x4*)(h_lds + ldsw[1]) = h1;
      if (!(ownj[2] && t>0)) *(u32x4*)(h_lds + ldsw[2]) = h2;
      if (!(ownj[3] && t>0)) *(u32x4*)(h_lds + ldsw[3]) = h3;
    }
    __syncthreads();

    // --- prefetch xg(t+1) (plain L2 loads; consumed next iteration) ---
    unsigned short xfn=xgf, xin=xgi, xon=xgo, xcn=xgc;
    if (t+1 < T_STEPS && tid < 256){
      const unsigned short* xn = XG2 + (((size_t)(t+1)*4 + grp)*32 + g)*1024;
      xfn = xn[tid]; xin = xn[256+tid]; xon = xn[512+tid]; xcn = xn[768+tid];
    }

    // --- 16x16 MFMA: accv = h(t) @ W[w] for this block's 16 cols ---
    f32x4 acc0 = {0.f,0.f,0.f,0.f}, acc1 = {0.f,0.f,0.f,0.f};
    #pragma unroll
    for (int kt=0; kt<16; kt+=2){
      bf16x8 a0 = *(const bf16x8*)(h_lds + l15*1024 + (((kt  )*64 + l4*16) ^ ((l15&7)<<4)));
      bf16x8 a1 = *(const bf16x8*)(h_lds + l15*1024 + (((kt+1)*64 + l4*16) ^ ((l15&7)<<4)));
      acc0 = __builtin_amdgcn_mfma_f32_16x16x32_bf16(a0, __builtin_bit_cast(bf16x8, breg[kt]),   acc0, 0,0,0);
      acc1 = __builtin_amdgcn_mfma_f32_16x16x32_bf16(a1, __builtin_bit_cast(bf16x8, breg[kt+1]), acc1, 0,0,0);
    }
    f32x4 accv = acc0 + acc1;

    if (w < 4){
      if (t < T_STEPS){
        #pragma unroll
        for (int r=0;r<4;r++) gate_lds[w][l4*4+r][l15] = accv[r];
      }
    } else if (t >= 1){
      #pragma unroll
      for (int r=0;r<4;r++)
        out[((size_t)(t-1)*64 + rowbase + l4*4 + r)*VOC + colbase + l15] = accv[r] + byv;
    }
    __syncthreads();

    // --- cell update; h(t+1) -> own LDS tile + coalesced fire-and-forget ring store ---
    if (t < T_STEPS && tid < 256){
      float gf = bf2f(xgf) + bfv + gate_lds[0][cr][cc];
      float gi = bf2f(xgi) + biv + gate_lds[1][cr][cc];
      float go = bf2f(xgo) + bov + gate_lds[2][cr][cc];
      float gc = bf2f(xgc) + bcv + gate_lds[3][cr][cc];
      float fv = sigm(gf), iv = sigm(gi), ov = sigm(go);
      c_val = fv*c_val + iv*tanhfast(gc);
      float hvf = ov*tanhfast(c_val);
      unsigned hb16 = f2bf(hvf);
      // own tile into LDS for step t+1 (staging skips it)
      *(unsigned short*)(h_lds + cr*1024 + ((g*32 + cc*2) ^ ((cr&7)<<4))) = (unsigned short)hb16;
      // ring store: 256 consecutive 2B -> full 64B lines, no drain needed
      char* hp = (char*)ring + (size_t)(t+1)*65536 + g*2048 + (rowbase+cr)*32 + cc*2;
      asm volatile("global_store_short %0, %1, off sc0 sc1"
                   :: "v"(hp), "v"(hb16) : "memory");
      if (t == T_STEPS-1){
        out[(size_t)TBV + (size_t)browg*512 + colg] = hvf;
        out[(size_t)TBV + 32768 + (size_t)browg*512 + colg] = c_val;
      }
    }
    xgf = xfn; xgi = xin; xgo = xon; xgc = xcn;
  }
}

extern "C" void kernel_launch(void* const* d_in, const int* in_sizes, int n_in,
                              void* d_out, int out_size, void* d_ws, size_t ws_size,
                              hipStream_t stream){
  const float* X    = (const float*)d_in[0];
  const float* state= (const float*)d_in[1];
  const float* cand = (const float*)d_in[2];
  const float* w_xf = (const float*)d_in[3];
  const float* w_hf = (const float*)d_in[4];
  const float* b_f  = (const float*)d_in[5];
  const float* w_xi = (const float*)d_in[6];
  const float* w_hi = (const float*)d_in[7];
  const float* b_i  = (const float*)d_in[8];
  const float* w_xo = (const float*)d_in[9];
  const float* w_ho = (const float*)d_in[10];
  const float* b_o  = (const float*)d_in[11];
  const float* w_xc = (const float*)d_in[12];
  const float* w_hc = (const float*)d_in[13];
  const float* b_c  = (const float*)d_in[14];
  const float* w_hy = (const float*)d_in[15];
  const float* b_y  = (const float*)d_in[16];
  float* out = (float*)d_out;

  char* ws = (char*)d_ws;
  unsigned short* XG2  = (unsigned short*)(ws);                 // 268,435,456 B
  // ring ALIASES Xb: Xb is consumed by k_gemm_xg, then poisoned as the h ring.
  unsigned short* Xb   = (unsigned short*)(ws + 268435456);     //  67,108,864 B
  unsigned short* ring = (unsigned short*)(ws + 268435456);     //  67,174,400 B (1025*65536)
  unsigned short* Wx4t = (unsigned short*)(ws + 335609856);     //   2,097,152 B
  unsigned short* Wt   = (unsigned short*)(ws + 337707008);     //   2,621,440 B -> end 340,328,448

  k_pack_x <<<16384,256,0,stream>>>(X, Xb);
  k_pack_wx<<<  512,256,0,stream>>>(w_xf,w_xi,w_xo,w_xc, Wx4t);
  k_pack_wh<<<  640,256,0,stream>>>(w_hf,w_hi,w_ho,w_hc,w_hy, Wt);
  k_gemm_xg<<< 8192,256,0,stream>>>(Xb, Wx4t, XG2);
  k_poison <<<16400,256,0,stream>>>((unsigned*)ring);
  k_init_h <<<   16,256,0,stream>>>(state, ring);
  k_scan   <<<  128,320,0,stream>>>(XG2, Wt, ring, cand, b_f,b_i,b_o,b_c,b_y, out);
}